// Round 1
// baseline (1446.074 us; speedup 1.0000x reference)
//
#include <hip/hip_runtime.h>
#include <math.h>

#define P    256
#define PM1  255

// ============================================================================
// K_t: transpose A1, A2 (256x256 row-major) into ws so the MLP kernel can read
// weight columns coalesced (A?T[j][n] = A?[n][j]).
// ============================================================================
__global__ void __launch_bounds__(256) k_transpose(
    const float* __restrict__ A1, const float* __restrict__ A2,
    float* __restrict__ A1T, float* __restrict__ A2T) {
  __shared__ float tile[64][65];
  const int bid = blockIdx.x;                // 0..31 (16 tiles per matrix)
  const float* src = (bid < 16) ? A1 : A2;
  float* dst       = (bid < 16) ? A1T : A2T;
  const int tl = bid & 15;
  const int R0 = (tl >> 2) << 6;
  const int C0 = (tl & 3) << 6;
  const int tx = threadIdx.x & 63;
  const int ty = threadIdx.x >> 6;           // 0..3
#pragma unroll
  for (int k = 0; k < 16; k++) {
    const int r = (k << 2) + ty;
    tile[r][tx] = src[(R0 + r) * P + C0 + tx];
  }
  __syncthreads();
#pragma unroll
  for (int k = 0; k < 16; k++) {
    const int c = (k << 2) + ty;
    dst[(C0 + c) * P + R0 + tx] = tile[tx][c];
  }
}

// ============================================================================
// K1: pass 1. One WG (512 thr, 8 waves) per batch. Wc (zero-padded to 256x256,
// compressed 255-space) lives in registers: wave (wrr,wcb), lane l owns rows
// r0=wrr*128+l, r1=r0+64, cols [wcb*64, wcb*64+64). Sequential over columns;
// Theta updated in place in global memory (same-WG RAW fenced per column).
// ============================================================================
__global__ void __launch_bounds__(512, 2) k_pass1(
    float* __restrict__ Th,                  // d_out, B x P x P, in-place
    const float* __restrict__ Wc,            // 255 x 255
    const float* __restrict__ bc) {          // 255
  const int b    = blockIdx.x;
  const int tid  = threadIdx.x;
  const int lane = tid & 63;
  const int wid  = tid >> 6;                 // 0..7
  const int wrr  = wid >> 2;                 // 0..1
  const int wcb  = wid & 3;                  // 0..3
  const int r0   = (wrr << 7) + lane;
  const int r1   = r0 + 64;
  const int cbase = wcb << 6;

  float w0[64], w1[64];
#pragma unroll
  for (int k = 0; k < 64; k++) {
    const int c = cbase + k;
    w0[k] = (r0 < PM1 && c < PM1) ? Wc[r0 * PM1 + c] : 0.f;
    w1[k] = (r1 < PM1 && c < PM1) ? Wc[r1 * PM1 + c] : 0.f;
  }

  __shared__ __align__(16) float t_lds[P];
  __shared__ float ypart[4][P];
  __shared__ float bc_lds[P];
  if (tid < P) bc_lds[tid] = (tid < PM1) ? bc[tid] : 0.f;

  float* __restrict__ ThB = Th + (size_t)b * P * P;
  __syncthreads();

  for (int col = 0; col < P; col++) {
    // ---- load th12 (compressed: t[j] = Th[j + (j>=col), col]) ----
    if (tid < P) {
      float v = 0.f;
      if (tid < PM1) {
        const int i = tid + (tid >= col ? 1 : 0);
        v = ThB[i * P + col];
      }
      t_lds[tid] = v;
    }
    __syncthreads();

    // ---- matvec th12n = Wc @ th12 (broadcast float4 LDS reads) ----
    float acc0 = 0.f, acc1 = 0.f;
#pragma unroll
    for (int k4 = 0; k4 < 16; k4++) {
      const float4 t4 = *(const float4*)&t_lds[cbase + (k4 << 2)];
      const float tt[4] = {t4.x, t4.y, t4.z, t4.w};
#pragma unroll
      for (int kk = 0; kk < 4; kk++) {
        acc0 = fmaf(w0[(k4 << 2) + kk], tt[kk], acc0);
        acc1 = fmaf(w1[(k4 << 2) + kk], tt[kk], acc1);
      }
    }
    ypart[wcb][r0] = acc0;
    ypart[wcb][r1] = acc1;
    __syncthreads();

    // ---- reduce, bias, scale, write column + symmetric row ----
    if (tid < PM1) {
      const float y = (ypart[0][tid] + ypart[1][tid] + ypart[2][tid] +
                       ypart[3][tid] + bc_lds[tid]) * 0.0625f;  // 1/sqrt(256)
      const int iout = tid + (tid >= col ? 1 : 0);
      ThB[iout * P + col] = y;
      ThB[col * P + iout] = y;
    }
    __threadfence_block();   // drain stores: next column re-reads them
    __syncthreads();
  }
}

// ============================================================================
// K2: MLP for ALL (b,col) pairs at once (gy only depends on post-pass1 Theta).
// m = b*256 + col. 16 rows per WG (same b). feats/h in LDS; weights read
// coalesced from transposed copies; fp32 throughout (matches reference).
// ============================================================================
__global__ void __launch_bounds__(256, 4) k_mlp(
    const float* __restrict__ Th,            // post-pass1 Theta (d_out)
    const float* __restrict__ A1T, const float* __restrict__ b1,
    const float* __restrict__ A2T, const float* __restrict__ b2,
    const float* __restrict__ A3,  const float* __restrict__ b3,
    float* __restrict__ gy) {
  const int m0 = blockIdx.x << 4;            // 16 rows per WG
  const int b  = m0 >> 8;
  const int c0 = m0 & (P - 1);
  const int t  = threadIdx.x;

  __shared__ __align__(16) float fbuf[16][260];   // feats, then h2
  __shared__ __align__(16) float hbuf[16][260];   // h1
  __shared__ float A3_lds[P];
  if (t < P) A3_lds[t] = A3[t];

  const float* __restrict__ ThB = Th + (size_t)b * P * P;

  // ---- build feats rows: feats = [Th[c,c], th12...] for c = c0..c0+15 ----
  {
    const int cc = t & 15;
    const int dr = t >> 4;
    const int c  = c0 + cc;
#pragma unroll
    for (int ii = 0; ii < 16; ii++) {
      const int i = (ii << 4) + dr;
      const float v = ThB[i * P + c];
      const int pos = (i == c) ? 0 : (i < c ? i + 1 : i);
      fbuf[cc][pos] = v;
    }
  }
  __syncthreads();

  // ---- layer 1: h1 = relu(feats @ A1^T + b1), thread t owns output col t ----
  {
    float acc[16];
    const float bv = b1[t];
#pragma unroll
    for (int r = 0; r < 16; r++) acc[r] = bv;
    for (int j4 = 0; j4 < 64; j4++) {
      const int j = j4 << 2;
      const float a0 = A1T[(j + 0) * P + t];
      const float a1 = A1T[(j + 1) * P + t];
      const float a2 = A1T[(j + 2) * P + t];
      const float a3 = A1T[(j + 3) * P + t];
#pragma unroll
      for (int r = 0; r < 16; r++) {
        const float4 f4 = *(const float4*)&fbuf[r][j];   // uniform -> broadcast
        acc[r] = fmaf(f4.x, a0, acc[r]);
        acc[r] = fmaf(f4.y, a1, acc[r]);
        acc[r] = fmaf(f4.z, a2, acc[r]);
        acc[r] = fmaf(f4.w, a3, acc[r]);
      }
    }
#pragma unroll
    for (int r = 0; r < 16; r++) hbuf[r][t] = fmaxf(acc[r], 0.f);
  }
  __syncthreads();

  // ---- layer 2: h2 = relu(h1 @ A2^T + b2), writes into fbuf (feats dead) ----
  {
    float acc[16];
    const float bv = b2[t];
#pragma unroll
    for (int r = 0; r < 16; r++) acc[r] = bv;
    for (int j4 = 0; j4 < 64; j4++) {
      const int j = j4 << 2;
      const float a0 = A2T[(j + 0) * P + t];
      const float a1 = A2T[(j + 1) * P + t];
      const float a2 = A2T[(j + 2) * P + t];
      const float a3 = A2T[(j + 3) * P + t];
#pragma unroll
      for (int r = 0; r < 16; r++) {
        const float4 f4 = *(const float4*)&hbuf[r][j];
        acc[r] = fmaf(f4.x, a0, acc[r]);
        acc[r] = fmaf(f4.y, a1, acc[r]);
        acc[r] = fmaf(f4.z, a2, acc[r]);
        acc[r] = fmaf(f4.w, a3, acc[r]);
      }
    }
    __syncthreads();   // all h1 reads done before overwriting fbuf? (fbuf!=hbuf: safe) — keep for clarity
#pragma unroll
    for (int r = 0; r < 16; r++) fbuf[r][t] = fmaxf(acc[r], 0.f);
  }
  __syncthreads();

  // ---- layer 3: gy = exp(h2 @ A3^T + b3); 16 threads per row ----
  {
    const int r = t >> 4, sub = t & 15;
    float p = 0.f;
#pragma unroll
    for (int jj = 0; jj < 16; jj++) {
      const int j = (jj << 4) + sub;
      p = fmaf(fbuf[r][j], A3_lds[j], p);
    }
    p += __shfl_xor(p, 1);
    p += __shfl_xor(p, 2);
    p += __shfl_xor(p, 4);
    p += __shfl_xor(p, 8);
    if (sub == 0) gy[m0 + r] = expf(p + b3[0]);
  }
}

// ============================================================================
// K3: pass 2. One WG (512 thr) per batch; W (256x256 fp32) register-resident
// (128 VGPR/lane). Full-space rank-1 recursion:
//   a = W[:,col]; w22 = a[col]; t = Theta1[:,col], t[col]=0
//   y = W@t; s = (a.t)/w22; v = y - s*a  (v[col]==0)
//   z = -v, z[col] = 1;  schur = -t.z
//   Theta[col,col] = gy + schur;  W += (-1/w22) a a^T + (1/gy) z z^T
// Only the diagonal of Theta is written (matches reference exactly).
// ============================================================================
__global__ void __launch_bounds__(512, 2) k_pass2(
    float* __restrict__ Th,                  // d_out (Theta after pass1)
    const float* __restrict__ Winit,         // B x P x P
    const float* __restrict__ gy) {          // B*P, [b*256 + col]
  const int b    = blockIdx.x;
  const int tid  = threadIdx.x;
  const int lane = tid & 63;
  const int wid  = tid >> 6;
  const int wrr  = wid >> 2;
  const int wcb  = wid & 3;
  const int r0   = (wrr << 7) + lane;
  const int r1   = r0 + 64;
  const int cbase = wcb << 6;

  // ---- load W_init into registers ----
  float w0[64], w1[64];
  const float* __restrict__ WB = Winit + (size_t)b * P * P;
#pragma unroll
  for (int k4 = 0; k4 < 16; k4++) {
    const float4 v0 = *(const float4*)&WB[r0 * P + cbase + (k4 << 2)];
    const float4 v1 = *(const float4*)&WB[r1 * P + cbase + (k4 << 2)];
    w0[(k4 << 2) + 0] = v0.x; w0[(k4 << 2) + 1] = v0.y;
    w0[(k4 << 2) + 2] = v0.z; w0[(k4 << 2) + 3] = v0.w;
    w1[(k4 << 2) + 0] = v1.x; w1[(k4 << 2) + 1] = v1.y;
    w1[(k4 << 2) + 2] = v1.z; w1[(k4 << 2) + 3] = v1.w;
  }

  float* __restrict__ ThB = Th + (size_t)b * P * P;
  const float* __restrict__ gyB = gy + b * P;

  __shared__ __align__(16) float t_lds[P];
  __shared__ __align__(16) float a_lds[P];
  __shared__ __align__(16) float z_lds[P];
  __shared__ float ypart[4][P];
  __shared__ float red[8];

  // prefetch t for col 0 (Theta off-diag is static during pass 2)
  float tv = 0.f;
  if (tid < P) tv = ThB[tid * P];
  __syncthreads();

  for (int col = 0; col < P; col++) {
    const int kcol  = col & 63;
    const int wccol = col >> 6;
    const float gyv = gyB[col];

    // ---- phase A: t and a into LDS ----
    if (tid < P) t_lds[tid] = (tid == col) ? 0.f : tv;
    if (wcb == wccol) {
      float av0 = 0.f, av1 = 0.f;
#pragma unroll
      for (int k = 0; k < 64; k++) {
        if (k == kcol) { av0 = w0[k]; av1 = w1[k]; }
      }
      a_lds[r0] = av0;
      a_lds[r1] = av1;
    }
    __syncthreads();                               // B1
    // prefetch next column's t (independent of all updates)
    if (tid < P && col < PM1) tv = ThB[tid * P + col + 1];

    // ---- phase B: w22 and a.t ----
    const float w22 = a_lds[col];
    if (tid < P) {
      float pp = a_lds[tid] * t_lds[tid];
      pp += __shfl_xor(pp, 1);  pp += __shfl_xor(pp, 2);
      pp += __shfl_xor(pp, 4);  pp += __shfl_xor(pp, 8);
      pp += __shfl_xor(pp, 16); pp += __shfl_xor(pp, 32);
      if (lane == 0) red[wid] = pp;
    }
    __syncthreads();                               // B2
    const float s = (red[0] + red[1] + red[2] + red[3]) / w22;

    // ---- phase C: y = W @ t ----
    float acc0 = 0.f, acc1 = 0.f;
#pragma unroll
    for (int k4 = 0; k4 < 16; k4++) {
      const float4 t4 = *(const float4*)&t_lds[cbase + (k4 << 2)];
      const float tt[4] = {t4.x, t4.y, t4.z, t4.w};
#pragma unroll
      for (int kk = 0; kk < 4; kk++) {
        acc0 = fmaf(w0[(k4 << 2) + kk], tt[kk], acc0);
        acc1 = fmaf(w1[(k4 << 2) + kk], tt[kk], acc1);
      }
    }
    ypart[wcb][r0] = acc0;
    ypart[wcb][r1] = acc1;
    __syncthreads();                               // B3

    // ---- phase D: v, z, schur; write diagonal ----
    if (tid < P) {
      const float y = ypart[0][tid] + ypart[1][tid] +
                      ypart[2][tid] + ypart[3][tid];
      const float v = y - a_lds[tid] * s;
      const float z = (tid == col) ? 1.f : -v;
      z_lds[tid] = z;
      float pp = t_lds[tid] * z;                   // schur = -sum(t*z)
      pp += __shfl_xor(pp, 1);  pp += __shfl_xor(pp, 2);
      pp += __shfl_xor(pp, 4);  pp += __shfl_xor(pp, 8);
      pp += __shfl_xor(pp, 16); pp += __shfl_xor(pp, 32);
      if (lane == 0) red[wid] = pp;
    }
    __syncthreads();                               // B4
    const float schur = -(red[0] + red[1] + red[2] + red[3]);
    if (tid == 0) ThB[col * P + col] = gyv + schur;

    // ---- phase E: W += (-1/w22) a a^T + (1/gy) z z^T ----
    const float c1 = -1.f / w22;
    const float c2 = 1.f / gyv;
    const float pa0 = c1 * a_lds[r0], pa1 = c1 * a_lds[r1];
    const float pz0 = c2 * z_lds[r0], pz1 = c2 * z_lds[r1];
#pragma unroll
    for (int k4 = 0; k4 < 16; k4++) {
      const float4 a4 = *(const float4*)&a_lds[cbase + (k4 << 2)];
      const float4 z4 = *(const float4*)&z_lds[cbase + (k4 << 2)];
      const float aa[4] = {a4.x, a4.y, a4.z, a4.w};
      const float zz[4] = {z4.x, z4.y, z4.z, z4.w};
#pragma unroll
      for (int kk = 0; kk < 4; kk++) {
        const int k = (k4 << 2) + kk;
        w0[k] = fmaf(pa0, aa[kk], fmaf(pz0, zz[kk], w0[k]));
        w1[k] = fmaf(pa1, aa[kk], fmaf(pz1, zz[kk], w1[k]));
      }
    }
    __syncthreads();                               // B5: protect t/a/z LDS
  }
}

// ============================================================================
extern "C" void kernel_launch(void* const* d_in, const int* in_sizes, int n_in,
                              void* d_out, int out_size, void* d_ws, size_t ws_size,
                              hipStream_t stream) {
  (void)in_sizes; (void)n_in; (void)out_size; (void)ws_size;
  const float* Theta = (const float*)d_in[0];
  // d_in[1] = W_init, d_in[2] = Wc, d_in[3] = bc,
  // d_in[4] = A1, d_in[5] = b1, d_in[6] = A2, d_in[7] = b2,
  // d_in[8] = A3, d_in[9] = b3
  const float* Winit = (const float*)d_in[1];
  const float* Wc    = (const float*)d_in[2];
  const float* bc    = (const float*)d_in[3];
  const float* A1    = (const float*)d_in[4];
  const float* b1    = (const float*)d_in[5];
  const float* A2    = (const float*)d_in[6];
  const float* b2    = (const float*)d_in[7];
  const float* A3    = (const float*)d_in[8];
  const float* b3    = (const float*)d_in[9];
  float* out = (float*)d_out;

  float* A1T = (float*)d_ws;             // 256*256 floats
  float* A2T = A1T + P * P;              // 256*256 floats
  float* gy  = A2T + P * P;              // 256*256 floats (65536)

  // Theta -> d_out; pass1/pass2 operate in place on d_out.
  hipMemcpyAsync(out, Theta, (size_t)256 * P * P * sizeof(float),
                 hipMemcpyDeviceToDevice, stream);

  k_transpose<<<32, 256, 0, stream>>>(A1, A2, A1T, A2T);
  k_pass1<<<256, 512, 0, stream>>>(out, Wc, bc);
  k_mlp<<<4096, 256, 0, stream>>>(out, A1T, b1, A2T, b2, A3, b3, gy);
  k_pass2<<<256, 512, 0, stream>>>(out, Winit, gy);
}

// Round 2
// 1409.404 us; speedup vs baseline: 1.0260x; 1.0260x over previous
//
#include <hip/hip_runtime.h>
#include <math.h>

#define P    256
#define PM1  255

// ============================================================================
// K_t: transpose A1, A2 (256x256 row-major) into ws so the MLP kernel can read
// weight columns coalesced (A?T[j][n] = A?[n][j]).
// ============================================================================
__global__ void __launch_bounds__(256) k_transpose(
    const float* __restrict__ A1, const float* __restrict__ A2,
    float* __restrict__ A1T, float* __restrict__ A2T) {
  __shared__ float tile[64][65];
  const int bid = blockIdx.x;                // 0..31 (16 tiles per matrix)
  const float* src = (bid < 16) ? A1 : A2;
  float* dst       = (bid < 16) ? A1T : A2T;
  const int tl = bid & 15;
  const int R0 = (tl >> 2) << 6;
  const int C0 = (tl & 3) << 6;
  const int tx = threadIdx.x & 63;
  const int ty = threadIdx.x >> 6;           // 0..3
#pragma unroll
  for (int k = 0; k < 16; k++) {
    const int r = (k << 2) + ty;
    tile[r][tx] = src[(R0 + r) * P + C0 + tx];
  }
  __syncthreads();
#pragma unroll
  for (int k = 0; k < 16; k++) {
    const int c = (k << 2) + ty;
    dst[(C0 + c) * P + R0 + tx] = tile[tx][c];
  }
}

// ============================================================================
// K1: pass 1. One WG (512 thr, 8 waves) per batch. Wc (zero-padded, compressed
// 255-space) register-resident. 2 barriers/col. t(col+1) prefetched during the
// matvec window via the SYMMETRIC row read (Theta stays symmetric in pass 1);
// the only RAW element t_next[col] is patched from this column's computed y.
// No threadfence needed: __syncthreads() makes block-global writes visible.
// ============================================================================
__global__ void __launch_bounds__(512, 2) k_pass1(
    float* __restrict__ Th,                  // d_out, B x P x P, in-place
    const float* __restrict__ Wc,            // 255 x 255
    const float* __restrict__ bc) {          // 255
  const int b    = blockIdx.x;
  const int tid  = threadIdx.x;
  const int wid  = tid >> 6;                 // 0..7
  const int lane = tid & 63;
  const int wrr  = wid >> 2;                 // 0..1
  const int wcb  = wid & 3;                  // 0..3
  const int r0   = (wrr << 7) + lane;
  const int r1   = r0 + 64;
  const int cbase = wcb << 6;

  float w0[64], w1[64];
#pragma unroll
  for (int k = 0; k < 64; k++) {
    const int c = cbase + k;
    w0[k] = (r0 < PM1 && c < PM1) ? Wc[r0 * PM1 + c] : 0.f;
    w1[k] = (r1 < PM1 && c < PM1) ? Wc[r1 * PM1 + c] : 0.f;
  }

  __shared__ __align__(16) float t_buf[2][P];
  __shared__ float ypart[4][P];
  __shared__ float bc_lds[P];
  if (tid < P) bc_lds[tid] = (tid < PM1) ? bc[tid] : 0.f;

  float* __restrict__ ThB = Th + (size_t)b * P * P;
  // init t(0): row 0 (symmetric): t[jj] = Th[0, jj+1]
  if (tid < P) t_buf[0][tid] = (tid < PM1) ? ThB[tid + 1] : 0.f;

  int p = 0;
  for (int col = 0; col < P; col++) {
    const int pn = p ^ 1;
    __syncthreads();                               // B1: t(col) ready
    // ---- matvec th12n = Wc @ th12 (broadcast float4 LDS reads) ----
    float acc0 = 0.f, acc1 = 0.f;
    const float4* tb = (const float4*)&t_buf[p][cbase];
#pragma unroll
    for (int k4 = 0; k4 < 16; k4++) {
      const float4 tv = tb[k4];
      acc0 = fmaf(w0[(k4 << 2) + 0], tv.x, acc0);
      acc0 = fmaf(w0[(k4 << 2) + 1], tv.y, acc0);
      acc0 = fmaf(w0[(k4 << 2) + 2], tv.z, acc0);
      acc0 = fmaf(w0[(k4 << 2) + 3], tv.w, acc0);
      acc1 = fmaf(w1[(k4 << 2) + 0], tv.x, acc1);
      acc1 = fmaf(w1[(k4 << 2) + 1], tv.y, acc1);
      acc1 = fmaf(w1[(k4 << 2) + 2], tv.z, acc1);
      acc1 = fmaf(w1[(k4 << 2) + 3], tv.w, acc1);
    }
    ypart[wcb][r0] = acc0;
    ypart[wcb][r1] = acc1;
    // ---- prefetch t(col+1) via symmetric ROW col+1 (coalesced) ----
    float tnext = 0.f;
    if (col < PM1 && tid < PM1) {
      const int i = tid + (tid >= col + 1 ? 1 : 0);
      tnext = ThB[(col + 1) * P + i];              // == Th[i, col+1] (symmetry)
    }
    __syncthreads();                               // B2: ypart ready
    // ---- reduce, bias, scale, write column + symmetric row; patch t ----
    if (tid < PM1) {
      const float y = (ypart[0][tid] + ypart[1][tid] + ypart[2][tid] +
                       ypart[3][tid] + bc_lds[tid]) * 0.0625f;  // 1/sqrt(256)
      const int iout = tid + (tid >= col ? 1 : 0);
      ThB[iout * P + col] = y;
      ThB[col * P + iout] = y;
      if (col < PM1) t_buf[pn][tid] = (tid == col) ? y : tnext;
    } else if (tid == PM1) {
      t_buf[pn][PM1] = 0.f;                        // keep zero pad
    }
    p = pn;
  }
}

// ============================================================================
// K2: MLP for ALL (b,col) pairs at once (gy only depends on post-pass1 Theta).
// ============================================================================
__global__ void __launch_bounds__(256, 4) k_mlp(
    const float* __restrict__ Th,            // post-pass1 Theta (d_out)
    const float* __restrict__ A1T, const float* __restrict__ b1,
    const float* __restrict__ A2T, const float* __restrict__ b2,
    const float* __restrict__ A3,  const float* __restrict__ b3,
    float* __restrict__ gy) {
  const int m0 = blockIdx.x << 4;            // 16 rows per WG
  const int b  = m0 >> 8;
  const int c0 = m0 & (P - 1);
  const int t  = threadIdx.x;

  __shared__ __align__(16) float fbuf[16][260];   // feats, then h2
  __shared__ __align__(16) float hbuf[16][260];   // h1
  __shared__ float A3_lds[P];
  if (t < P) A3_lds[t] = A3[t];

  const float* __restrict__ ThB = Th + (size_t)b * P * P;

  // ---- build feats rows: feats = [Th[c,c], th12...] for c = c0..c0+15 ----
  {
    const int cc = t & 15;
    const int dr = t >> 4;
    const int c  = c0 + cc;
#pragma unroll
    for (int ii = 0; ii < 16; ii++) {
      const int i = (ii << 4) + dr;
      const float v = ThB[i * P + c];
      const int pos = (i == c) ? 0 : (i < c ? i + 1 : i);
      fbuf[cc][pos] = v;
    }
  }
  __syncthreads();

  // ---- layer 1: h1 = relu(feats @ A1^T + b1) ----
  {
    float acc[16];
    const float bv = b1[t];
#pragma unroll
    for (int r = 0; r < 16; r++) acc[r] = bv;
    for (int j4 = 0; j4 < 64; j4++) {
      const int j = j4 << 2;
      const float a0 = A1T[(j + 0) * P + t];
      const float a1 = A1T[(j + 1) * P + t];
      const float a2 = A1T[(j + 2) * P + t];
      const float a3 = A1T[(j + 3) * P + t];
#pragma unroll
      for (int r = 0; r < 16; r++) {
        const float4 f4 = *(const float4*)&fbuf[r][j];
        acc[r] = fmaf(f4.x, a0, acc[r]);
        acc[r] = fmaf(f4.y, a1, acc[r]);
        acc[r] = fmaf(f4.z, a2, acc[r]);
        acc[r] = fmaf(f4.w, a3, acc[r]);
      }
    }
#pragma unroll
    for (int r = 0; r < 16; r++) hbuf[r][t] = fmaxf(acc[r], 0.f);
  }
  __syncthreads();

  // ---- layer 2: h2 = relu(h1 @ A2^T + b2) ----
  {
    float acc[16];
    const float bv = b2[t];
#pragma unroll
    for (int r = 0; r < 16; r++) acc[r] = bv;
    for (int j4 = 0; j4 < 64; j4++) {
      const int j = j4 << 2;
      const float a0 = A2T[(j + 0) * P + t];
      const float a1 = A2T[(j + 1) * P + t];
      const float a2 = A2T[(j + 2) * P + t];
      const float a3 = A2T[(j + 3) * P + t];
#pragma unroll
      for (int r = 0; r < 16; r++) {
        const float4 f4 = *(const float4*)&hbuf[r][j];
        acc[r] = fmaf(f4.x, a0, acc[r]);
        acc[r] = fmaf(f4.y, a1, acc[r]);
        acc[r] = fmaf(f4.z, a2, acc[r]);
        acc[r] = fmaf(f4.w, a3, acc[r]);
      }
    }
    __syncthreads();
#pragma unroll
    for (int r = 0; r < 16; r++) fbuf[r][t] = fmaxf(acc[r], 0.f);
  }
  __syncthreads();

  // ---- layer 3: gy = exp(h2 @ A3^T + b3); 16 threads per row ----
  {
    const int r = t >> 4, sub = t & 15;
    float pq = 0.f;
#pragma unroll
    for (int jj = 0; jj < 16; jj++) {
      const int j = (jj << 4) + sub;
      pq = fmaf(fbuf[r][j], A3_lds[j], pq);
    }
    pq += __shfl_xor(pq, 1);
    pq += __shfl_xor(pq, 2);
    pq += __shfl_xor(pq, 4);
    pq += __shfl_xor(pq, 8);
    if (sub == 0) gy[m0 + r] = expf(pq + b3[0]);
  }
}

// ============================================================================
// K3: pass 2. One WG (512 thr) per batch; W (256x256 fp32) register-resident.
// W stays SYMMETRIC under both rank-1 updates => column col == row col, which
// one lane owns contiguously: extraction = 16 ds_write_b128 from that lane.
// 3 barriers/col: B1 (t,a ready), B3 (ypart ready), B4 (z ready).
//   a = W[:,col]; w22 = a[col]; t = Theta1[:,col], t[col]=0
//   y = W@t; s = (a.t)/w22; v = y - s*a  (v[col]==0)
//   z = -v, z[col] = 1;  schur = t.y - s*(a.t)
//   Theta[col,col] = gy + schur;  W += (-1/w22) a a^T + (1/gy) z z^T
// ============================================================================
__global__ void __launch_bounds__(512, 2) k_pass2(
    float* __restrict__ Th,                  // d_out (Theta after pass1)
    const float* __restrict__ Winit,         // B x P x P
    const float* __restrict__ gy) {          // B*P, [b*256 + col]
  const int b    = blockIdx.x;
  const int tid  = threadIdx.x;
  const int lane = tid & 63;
  const int wid  = tid >> 6;
  const int wrr  = wid >> 2;
  const int wcb  = wid & 3;
  const int r0   = (wrr << 7) + lane;
  const int r1   = r0 + 64;
  const int cbase = wcb << 6;
  const int e0   = lane << 2;

  // ---- load W_init into registers ----
  float w0[64], w1[64];
  const float* __restrict__ WB = Winit + (size_t)b * P * P;
#pragma unroll
  for (int k4 = 0; k4 < 16; k4++) {
    const float4 v0 = *(const float4*)&WB[r0 * P + cbase + (k4 << 2)];
    const float4 v1 = *(const float4*)&WB[r1 * P + cbase + (k4 << 2)];
    w0[(k4 << 2) + 0] = v0.x; w0[(k4 << 2) + 1] = v0.y;
    w0[(k4 << 2) + 2] = v0.z; w0[(k4 << 2) + 3] = v0.w;
    w1[(k4 << 2) + 0] = v1.x; w1[(k4 << 2) + 1] = v1.y;
    w1[(k4 << 2) + 2] = v1.z; w1[(k4 << 2) + 3] = v1.w;
  }

  float* __restrict__ ThB = Th + (size_t)b * P * P;
  const float* __restrict__ gyB = gy + b * P;

  __shared__ __align__(16) float t_buf[2][P];
  __shared__ __align__(16) float a_buf[2][P];
  __shared__ __align__(16) float z_lds[P];
  __shared__ float ypart[4][P];

  // init: t(0) from ROW 0 of Theta (symmetric after pass1); a(0) = row 0 of W
  if (tid < P) t_buf[0][tid] = (tid == 0) ? 0.f : ThB[tid];
  if (r0 == 0) {
    float4* dst = (float4*)&a_buf[0][cbase];
#pragma unroll
    for (int k4 = 0; k4 < 16; k4++)
      dst[k4] = make_float4(w0[(k4 << 2) + 0], w0[(k4 << 2) + 1],
                            w0[(k4 << 2) + 2], w0[(k4 << 2) + 3]);
  }
  float gyv = gyB[0];

  int p = 0;
  for (int col = 0; col < P; col++) {
    const int pn = p ^ 1;
    __syncthreads();                               // B1: t,a(col) ready

    // ---- wave-redundant full dot a.t (64 lanes x 4 elems = all 256) ----
    const float4 a4 = *(const float4*)&a_buf[p][e0];
    const float4 t4 = *(const float4*)&t_buf[p][e0];
    float pp = a4.x * t4.x + a4.y * t4.y + a4.z * t4.z + a4.w * t4.w;
    pp += __shfl_xor(pp, 1);  pp += __shfl_xor(pp, 2);
    pp += __shfl_xor(pp, 4);  pp += __shfl_xor(pp, 8);
    pp += __shfl_xor(pp, 16); pp += __shfl_xor(pp, 32);
    const float at  = pp;
    const float w22 = a_buf[p][col];               // uniform -> broadcast
    const float s   = at / w22;

    // ---- prefetch t(col+1) via ROW col+1 (off-diag static; diag zeroed) ----
    float tnext = 0.f, gynext = 0.f;
    if (col < PM1) {
      if (tid < P) tnext = ThB[(col + 1) * P + tid];
      gynext = gyB[col + 1];
    }

    // ---- matvec y = W @ t (uniform float4 LDS broadcasts) ----
    float acc0 = 0.f, acc1 = 0.f;
    const float4* tb = (const float4*)&t_buf[p][cbase];
#pragma unroll
    for (int k4 = 0; k4 < 16; k4++) {
      const float4 tv = tb[k4];
      acc0 = fmaf(w0[(k4 << 2) + 0], tv.x, acc0);
      acc0 = fmaf(w0[(k4 << 2) + 1], tv.y, acc0);
      acc0 = fmaf(w0[(k4 << 2) + 2], tv.z, acc0);
      acc0 = fmaf(w0[(k4 << 2) + 3], tv.w, acc0);
      acc1 = fmaf(w1[(k4 << 2) + 0], tv.x, acc1);
      acc1 = fmaf(w1[(k4 << 2) + 1], tv.y, acc1);
      acc1 = fmaf(w1[(k4 << 2) + 2], tv.z, acc1);
      acc1 = fmaf(w1[(k4 << 2) + 3], tv.w, acc1);
    }
    ypart[wcb][r0] = acc0;
    ypart[wcb][r1] = acc1;
    __syncthreads();                               // B3: ypart ready

    if (tid < P) {
      // ---- z vector (waves 0-3) + stage next t ----
      const float y = ypart[0][tid] + ypart[1][tid] +
                      ypart[2][tid] + ypart[3][tid];
      const float v = y - s * a_buf[p][tid];
      z_lds[tid] = (tid == col) ? 1.f : -v;
      if (col < PM1) t_buf[pn][tid] = (tid == col + 1) ? 0.f : tnext;
    } else if (wid == 4) {
      // ---- schur = t.y - s*(a.t)  (wave 4, redundant full dot) ----
      const float4 tt = *(const float4*)&t_buf[p][e0];
      const float4 q0 = *(const float4*)&ypart[0][e0];
      const float4 q1 = *(const float4*)&ypart[1][e0];
      const float4 q2 = *(const float4*)&ypart[2][e0];
      const float4 q3 = *(const float4*)&ypart[3][e0];
      float sp = tt.x * (q0.x + q1.x + q2.x + q3.x)
               + tt.y * (q0.y + q1.y + q2.y + q3.y)
               + tt.z * (q0.z + q1.z + q2.z + q3.z)
               + tt.w * (q0.w + q1.w + q2.w + q3.w);
      sp += __shfl_xor(sp, 1);  sp += __shfl_xor(sp, 2);
      sp += __shfl_xor(sp, 4);  sp += __shfl_xor(sp, 8);
      sp += __shfl_xor(sp, 16); sp += __shfl_xor(sp, 32);
      if (lane == 0) ThB[col * P + col] = gyv + (sp - s * at);
    }
    __syncthreads();                               // B4: z ready

    // ---- rank-2 update W += c1 a a^T + c2 z z^T ----
    const float c1 = -1.f / w22;
    const float c2 = 1.f / gyv;
    const float pa0 = c1 * a_buf[p][r0], pa1 = c1 * a_buf[p][r1];
    const float pz0 = c2 * z_lds[r0],    pz1 = c2 * z_lds[r1];
    const float4* ab = (const float4*)&a_buf[p][cbase];
    const float4* zb = (const float4*)&z_lds[cbase];
#pragma unroll
    for (int k4 = 0; k4 < 16; k4++) {
      const float4 av = ab[k4];
      const float4 zv = zb[k4];
      w0[(k4 << 2) + 0] = fmaf(pa0, av.x, fmaf(pz0, zv.x, w0[(k4 << 2) + 0]));
      w0[(k4 << 2) + 1] = fmaf(pa0, av.y, fmaf(pz0, zv.y, w0[(k4 << 2) + 1]));
      w0[(k4 << 2) + 2] = fmaf(pa0, av.z, fmaf(pz0, zv.z, w0[(k4 << 2) + 2]));
      w0[(k4 << 2) + 3] = fmaf(pa0, av.w, fmaf(pz0, zv.w, w0[(k4 << 2) + 3]));
      w1[(k4 << 2) + 0] = fmaf(pa1, av.x, fmaf(pz1, zv.x, w1[(k4 << 2) + 0]));
      w1[(k4 << 2) + 1] = fmaf(pa1, av.y, fmaf(pz1, zv.y, w1[(k4 << 2) + 1]));
      w1[(k4 << 2) + 2] = fmaf(pa1, av.z, fmaf(pz1, zv.z, w1[(k4 << 2) + 2]));
      w1[(k4 << 2) + 3] = fmaf(pa1, av.w, fmaf(pz1, zv.w, w1[(k4 << 2) + 3]));
    }

    // ---- extract a(col+1) = row col+1 of UPDATED W (symmetry) ----
    if (r0 == col + 1) {
      float4* dst = (float4*)&a_buf[pn][cbase];
#pragma unroll
      for (int k4 = 0; k4 < 16; k4++)
        dst[k4] = make_float4(w0[(k4 << 2) + 0], w0[(k4 << 2) + 1],
                              w0[(k4 << 2) + 2], w0[(k4 << 2) + 3]);
    } else if (r1 == col + 1) {
      float4* dst = (float4*)&a_buf[pn][cbase];
#pragma unroll
      for (int k4 = 0; k4 < 16; k4++)
        dst[k4] = make_float4(w1[(k4 << 2) + 0], w1[(k4 << 2) + 1],
                              w1[(k4 << 2) + 2], w1[(k4 << 2) + 3]);
    }

    gyv = gynext;
    p = pn;
  }
}

// ============================================================================
extern "C" void kernel_launch(void* const* d_in, const int* in_sizes, int n_in,
                              void* d_out, int out_size, void* d_ws, size_t ws_size,
                              hipStream_t stream) {
  (void)in_sizes; (void)n_in; (void)out_size; (void)ws_size;
  const float* Theta = (const float*)d_in[0];
  const float* Winit = (const float*)d_in[1];
  const float* Wc    = (const float*)d_in[2];
  const float* bc    = (const float*)d_in[3];
  const float* A1    = (const float*)d_in[4];
  const float* b1    = (const float*)d_in[5];
  const float* A2    = (const float*)d_in[6];
  const float* b2    = (const float*)d_in[7];
  const float* A3    = (const float*)d_in[8];
  const float* b3    = (const float*)d_in[9];
  float* out = (float*)d_out;

  float* A1T = (float*)d_ws;             // 256*256 floats
  float* A2T = A1T + P * P;              // 256*256 floats
  float* gyb = A2T + P * P;              // 256*256 floats (65536)

  hipMemcpyAsync(out, Theta, (size_t)256 * P * P * sizeof(float),
                 hipMemcpyDeviceToDevice, stream);

  k_transpose<<<32, 256, 0, stream>>>(A1, A2, A1T, A2T);
  k_pass1<<<256, 512, 0, stream>>>(out, Wc, bc);
  k_mlp<<<4096, 256, 0, stream>>>(out, A1T, b1, A2T, b2, A3, b3, gyb);
  k_pass2<<<256, 512, 0, stream>>>(out, Winit, gyb);
}